// Round 1
// baseline (1572.559 us; speedup 1.0000x reference)
//
#include <hip/hip_runtime.h>

#define T_ 1024
#define D_ 1024
#define B_ 4
#define H_ 16
#define DH_ 64
#define M_ (B_*T_)                 // 4096
#define NEG_ (-4294967295.0f)      // rounds to -2^32, same as jnp.float32(-2**32+1)

// ---------------- q_in = queries + 32*pe_q ----------------
__global__ __launch_bounds__(256) void prep_qin(const float* __restrict__ q,
                                                const float* __restrict__ pe,
                                                float* __restrict__ out, int n4)
{
    int i = blockIdx.x * 256 + threadIdx.x;
    if (i >= n4) return;
    const int pe_n4 = T_ * D_ / 4;          // 262144 (power of 2)
    float4 a = ((const float4*)q)[i];
    float4 p = ((const float4*)pe)[i & (pe_n4 - 1)];
    a.x += 32.f * p.x; a.y += 32.f * p.y; a.z += 32.f * p.z; a.w += 32.f * p.w;
    ((float4*)out)[i] = a;
}

// ---------------- generic fp32 GEMM: C = op(A(+32*pe)) @ B ----------------
// BM = TM*16, BN = 128, BK = 16, 256 threads, per-thread TM x 8.
// flags: 1 = relu on store, 2 = accumulate into C.
template <int TM>
__global__ __launch_bounds__(256) void gemm_f32(const float* __restrict__ A,
                                                const float* __restrict__ Bm,
                                                float* __restrict__ C,
                                                int M, int N, int K,
                                                const float* __restrict__ pe, int flags)
{
    constexpr int BM = TM * 16;
    __shared__ __align__(16) float As[16][BM + 4];   // [k][m] (transposed)
    __shared__ __align__(16) float Bs[16][132];      // [k][n]

    const int tid = threadIdx.x;
    const int m0 = blockIdx.y * BM;
    const int n0 = blockIdx.x * 128;
    const int q0 = (tid >> 4) * TM;
    const int p0 = (tid & 15) * 8;

    float acc[TM][8];
    #pragma unroll
    for (int i = 0; i < TM; ++i)
        #pragma unroll
        for (int j = 0; j < 8; ++j) acc[i][j] = 0.f;

    for (int k0 = 0; k0 < K; k0 += 16) {
        // stage A tile: BM x 16  (BM*4 float4s)
        #pragma unroll
        for (int s = 0; s < BM / 64; ++s) {
            int fl = s * 256 + tid;             // < BM*4
            int row = fl >> 2;
            int c4 = (fl & 3) << 2;
            float4 a = *(const float4*)(A + (size_t)(m0 + row) * K + k0 + c4);
            if (pe) {
                float4 p = *(const float4*)(pe + (size_t)((m0 + row) & (T_ - 1)) * D_ + k0 + c4);
                a.x += 32.f * p.x; a.y += 32.f * p.y; a.z += 32.f * p.z; a.w += 32.f * p.w;
            }
            As[c4 + 0][row] = a.x; As[c4 + 1][row] = a.y;
            As[c4 + 2][row] = a.z; As[c4 + 3][row] = a.w;
        }
        // stage B tile: 16 x 128  (512 float4s)
        #pragma unroll
        for (int s = 0; s < 2; ++s) {
            int fl = s * 256 + tid;
            int kk = fl >> 5;
            int c = (fl & 31) << 2;
            *(float4*)&Bs[kk][c] = *(const float4*)(Bm + (size_t)(k0 + kk) * N + n0 + c);
        }
        __syncthreads();

        #pragma unroll
        for (int kk = 0; kk < 16; ++kk) {
            float av[TM], bv[8];
            #pragma unroll
            for (int u = 0; u < TM / 4; ++u) {
                float4 a = *(float4*)&As[kk][q0 + u * 4];
                av[u*4+0] = a.x; av[u*4+1] = a.y; av[u*4+2] = a.z; av[u*4+3] = a.w;
            }
            {
                float4 b0 = *(float4*)&Bs[kk][p0];
                float4 b1 = *(float4*)&Bs[kk][p0 + 4];
                bv[0]=b0.x; bv[1]=b0.y; bv[2]=b0.z; bv[3]=b0.w;
                bv[4]=b1.x; bv[5]=b1.y; bv[6]=b1.z; bv[7]=b1.w;
            }
            #pragma unroll
            for (int i = 0; i < TM; ++i)
                #pragma unroll
                for (int j = 0; j < 8; ++j) acc[i][j] += av[i] * bv[j];
        }
        __syncthreads();
    }

    #pragma unroll
    for (int i = 0; i < TM; ++i) {
        size_t row = m0 + q0 + i;
        #pragma unroll
        for (int j4 = 0; j4 < 8; j4 += 4) {
            float4 v = make_float4(acc[i][j4], acc[i][j4+1], acc[i][j4+2], acc[i][j4+3]);
            if (flags & 1) {
                v.x = fmaxf(v.x, 0.f); v.y = fmaxf(v.y, 0.f);
                v.z = fmaxf(v.z, 0.f); v.w = fmaxf(v.w, 0.f);
            }
            float* cp = C + row * N + n0 + p0 + j4;
            if (flags & 2) {
                float4 o = *(const float4*)cp;
                v.x += o.x; v.y += o.y; v.z += o.z; v.w += o.w;
            }
            *(float4*)cp = v;
        }
    }
}

// ---------------- flash-style fp32 attention + residual ----------------
// block = (b, h, q-tile of 64); 256 threads; online softmax; masks fused.
__global__ __launch_bounds__(256) void attn(const float* __restrict__ Q,
                                            const float* __restrict__ Kp,
                                            const float* __restrict__ Vp,
                                            const float* __restrict__ q_in,
                                            const int* __restrict__ qlens,
                                            const int* __restrict__ klens,
                                            float* __restrict__ res)
{
    __shared__ __align__(16) float QsT[64][68];   // [d][q]
    __shared__ __align__(16) float KP[64][68];    // KsT [d][k]  then PT [k][q]
    __shared__ __align__(16) float Vs[64][68];    // [k][d]
    __shared__ float rowm[64], rowl[64], rowfac[64];

    const int tid = threadIdx.x;
    const int qt = blockIdx.x, h = blockIdx.y, b = blockIdx.z;
    const int qbase = qt * 64;
    const int qlen = qlens[b], klen = klens[b];

    // load Q tile transposed into QsT
    {
        int r = tid >> 2;
        int cc = (tid & 3) * 16;
        const float* src = Q + ((size_t)(b * T_ + qbase + r)) * D_ + h * DH_ + cc;
        #pragma unroll
        for (int u = 0; u < 4; ++u) {
            float4 v = *(const float4*)(src + u * 4);
            QsT[cc + u*4 + 0][r] = v.x; QsT[cc + u*4 + 1][r] = v.y;
            QsT[cc + u*4 + 2][r] = v.z; QsT[cc + u*4 + 3][r] = v.w;
        }
    }
    if (tid < 64) { rowm[tid] = -3.0e38f; rowl[tid] = 0.f; }

    const int q0 = (tid >> 4) * 4;   // row group (QK & PV)
    const int c0 = (tid & 15) * 4;   // k group in QK, d group in PV
    float acc[4][4] = {};

    for (int kb = 0; kb < 16; ++kb) {
        const int kbase = kb * 64;
        __syncthreads();   // prev PV done (KP,Vs free); also covers QsT/rowm init
        // stage K (transposed) and V
        {
            int r = tid >> 2;
            int cc = (tid & 3) * 16;
            const float* ksrc = Kp + ((size_t)(b * T_ + kbase + r)) * D_ + h * DH_ + cc;
            const float* vsrc = Vp + ((size_t)(b * T_ + kbase + r)) * D_ + h * DH_ + cc;
            #pragma unroll
            for (int u = 0; u < 4; ++u) {
                float4 v = *(const float4*)(ksrc + u * 4);
                KP[cc + u*4 + 0][r] = v.x; KP[cc + u*4 + 1][r] = v.y;
                KP[cc + u*4 + 2][r] = v.z; KP[cc + u*4 + 3][r] = v.w;
                *(float4*)&Vs[r][cc + u*4] = *(const float4*)(vsrc + u * 4);
            }
        }
        __syncthreads();
        // QK^T into registers
        float s[4][4] = {};
        #pragma unroll 8
        for (int d = 0; d < 64; ++d) {
            float4 qa = *(float4*)&QsT[d][q0];
            float4 ka = *(float4*)&KP[d][c0];
            float qv[4] = {qa.x, qa.y, qa.z, qa.w};
            float kv[4] = {ka.x, ka.y, ka.z, ka.w};
            #pragma unroll
            for (int i = 0; i < 4; ++i)
                #pragma unroll
                for (int j = 0; j < 4; ++j) s[i][j] += qv[i] * kv[j];
        }
        __syncthreads();   // all KsT reads done; KP becomes PT
        // scale + masks, write PT[k][q]
        #pragma unroll
        for (int i = 0; i < 4; ++i) {
            int gq = qbase + q0 + i;
            #pragma unroll
            for (int j = 0; j < 4; ++j) {
                int gk = kbase + c0 + j;
                float v = s[i][j] * 0.125f;
                if (gk >= klen || gk == gq) v = NEG_;
                KP[c0 + j][q0 + i] = v;
            }
        }
        __syncthreads();
        // online softmax: 4 lanes per q-row
        {
            int q = tid >> 2, g = tid & 3;
            float mx = -3.0e38f;
            #pragma unroll
            for (int kk = 0; kk < 16; ++kk) mx = fmaxf(mx, KP[g * 16 + kk][q]);
            mx = fmaxf(mx, __shfl_xor(mx, 1));
            mx = fmaxf(mx, __shfl_xor(mx, 2));
            float mold = rowm[q];
            float mnew = fmaxf(mold, mx);
            float sum = 0.f;
            #pragma unroll
            for (int kk = 0; kk < 16; ++kk) {
                int k = g * 16 + kk;
                float p = __expf(KP[k][q] - mnew);
                KP[k][q] = p;
                sum += p;
            }
            sum += __shfl_xor(sum, 1);
            sum += __shfl_xor(sum, 2);
            float fac = __expf(mold - mnew);
            if (g == 0) { rowm[q] = mnew; rowl[q] = rowl[q] * fac + sum; rowfac[q] = fac; }
        }
        __syncthreads();
        // PV: rescale + accumulate
        {
            float f[4];
            #pragma unroll
            for (int i = 0; i < 4; ++i) f[i] = rowfac[q0 + i];
            #pragma unroll
            for (int i = 0; i < 4; ++i)
                #pragma unroll
                for (int j = 0; j < 4; ++j) acc[i][j] *= f[i];
            #pragma unroll 8
            for (int k = 0; k < 64; ++k) {
                float4 pa = *(float4*)&KP[k][q0];
                float4 vb = *(float4*)&Vs[k][c0];
                float pv[4] = {pa.x, pa.y, pa.z, pa.w};
                float vv[4] = {vb.x, vb.y, vb.z, vb.w};
                #pragma unroll
                for (int i = 0; i < 4; ++i)
                    #pragma unroll
                    for (int j = 0; j < 4; ++j) acc[i][j] += pv[i] * vv[j];
            }
        }
    }
    // epilogue: out = qmask * acc/l + q_in  (residual)
    #pragma unroll
    for (int i = 0; i < 4; ++i) {
        int gq = qbase + q0 + i;
        float qm = (gq < qlen) ? 1.f : 0.f;
        float invl = qm / rowl[q0 + i];
        size_t off = ((size_t)(b * T_ + gq)) * D_ + h * DH_ + c0;
        float4 r0 = *(const float4*)(q_in + off);
        float4 o;
        o.x = acc[i][0] * invl + r0.x;
        o.y = acc[i][1] * invl + r0.y;
        o.z = acc[i][2] * invl + r0.z;
        o.w = acc[i][3] * invl + r0.w;
        *(float4*)(res + off) = o;
    }
}

// ---------------- mean over T ----------------
__global__ __launch_bounds__(256) void mean_kernel(const float* __restrict__ res,
                                                   float* __restrict__ out)
{
    __shared__ float part[4][64];
    int tid = threadIdx.x;
    int b = blockIdx.x >> 4;
    int dbase = (blockIdx.x & 15) * 64;
    int tq = tid >> 6, dd = tid & 63;
    int d = dbase + dd;
    float s = 0.f;
    const float* p = res + ((size_t)b * T_ + tq * 256) * D_ + d;
    for (int t = 0; t < 256; ++t) s += p[(size_t)t * D_];
    part[tq][dd] = s;
    __syncthreads();
    if (tq == 0)
        out[b * D_ + d] = (part[0][dd] + part[1][dd] + part[2][dd] + part[3][dd]) * (1.f / 1024.f);
}

extern "C" void kernel_launch(void* const* d_in, const int* in_sizes, int n_in,
                              void* d_out, int out_size, void* d_ws, size_t ws_size,
                              hipStream_t stream)
{
    const float* queries = (const float*)d_in[0];
    // d_in[1] keys: unused (source bug: k_in derives from PE'd queries)
    const int*   qlens   = (const int*)d_in[2];
    const int*   klens   = (const int*)d_in[3];
    const float* pe_q    = (const float*)d_in[4];
    const float* pe_k    = (const float*)d_in[5];
    const float* Wq      = (const float*)d_in[6];
    const float* Wk      = (const float*)d_in[7];
    const float* Wv      = (const float*)d_in[8];
    const float* fw1     = (const float*)d_in[9];
    const float* fw2     = (const float*)d_in[10];
    float* out = (float*)d_out;

    float* ws = (float*)d_ws;
    const size_t SZ = (size_t)M_ * D_;      // 4194304 floats = 16 MB
    float* q_in = ws;                        // [0, SZ)
    float* Qb   = ws + SZ;                   // [SZ, 2SZ)
    float* Kb   = ws + 2 * SZ;               // [2SZ, 3SZ)
    float* Vb   = ws + 3 * SZ;               // [3SZ, 4SZ)
    float* res  = ws + 4 * SZ;               // [4SZ, 5SZ)
    float* h1   = ws;                        // 4096x4096 = 4*SZ, reuses dead q_in/Q/K/V
    // total ws use: 5*SZ floats = 80 MB

    // 1) q_in = queries + 32*pe_q
    prep_qin<<<dim3(M_ * D_ / 4 / 256), dim3(256), 0, stream>>>(queries, pe_q, q_in, M_ * D_ / 4);
    // 2) projections (N=1024 -> BM=64 variant for 512 blocks)
    dim3 gP(D_ / 128, M_ / 64);
    gemm_f32<4><<<gP, 256, 0, stream>>>(q_in, Wq, Qb, M_, D_, D_, nullptr, 0);
    gemm_f32<4><<<gP, 256, 0, stream>>>(q_in, Wk, Kb, M_, D_, D_, pe_k, 0);   // k_in fused
    gemm_f32<4><<<gP, 256, 0, stream>>>(Kb, Wv, Vb, M_, D_, D_, nullptr, 0);  // V from projected K
    // 3) attention + residual
    attn<<<dim3(T_ / 64, H_, B_), 256, 0, stream>>>(Qb, Kb, Vb, q_in, qlens, klens, res);
    // 4) FFN
    dim3 gF1(4 * D_ / 128, M_ / 128);
    gemm_f32<8><<<gF1, 256, 0, stream>>>(res, fw1, h1, M_, 4 * D_, D_, nullptr, 1);     // relu
    dim3 gF2(D_ / 128, M_ / 64);
    gemm_f32<4><<<gF2, 256, 0, stream>>>(h1, fw2, res, M_, D_, 4 * D_, nullptr, 2);     // accumulate
    // 5) mean over T
    mean_kernel<<<dim3(64), 256, 0, stream>>>(res, out);
}

// Round 2
// 644.869 us; speedup vs baseline: 2.4386x; 2.4386x over previous
//
#include <hip/hip_runtime.h>

#define T_ 1024
#define D_ 1024
#define B_ 4
#define H_ 16
#define DH_ 64
#define M_ (B_*T_)                 // 4096
#define NEG_ (-4294967295.0f)

typedef __attribute__((ext_vector_type(8))) short bf16x8;
typedef __attribute__((ext_vector_type(4))) float f32x4;
typedef unsigned short ushort_t;

__device__ __forceinline__ float b2f(unsigned short u) {
    union { unsigned int i; float f; } v; v.i = ((unsigned int)u) << 16; return v.f;
}
__device__ __forceinline__ unsigned short f2b(float f) {
    unsigned int x = __float_as_uint(f);
    return (unsigned short)((x + 0x7fffu + ((x >> 16) & 1u)) >> 16);
}

typedef const unsigned int __attribute__((address_space(1)))* gas_p;
typedef unsigned int __attribute__((address_space(3)))* las_p;
__device__ __forceinline__ void gl_lds16(const void* g, void* l) {
    __builtin_amdgcn_global_load_lds((gas_p)g, (las_p)l, 16, 0, 0);
}

// ---------------- conv: A2q = [hi(q_in)|lo(q_in)], q16 = hi(q_in) ----------------
__global__ __launch_bounds__(256) void conv_q(const float* __restrict__ q,
                                              const float* __restrict__ peq,
                                              unsigned short* __restrict__ A2,
                                              unsigned short* __restrict__ q16)
{
    int i = blockIdx.x * 256 + threadIdx.x;          // 1M threads, 4 elems each
    int m = i >> 8, c4 = (i & 255) << 2;
    float4 qv = *(const float4*)(q + (size_t)m * D_ + c4);
    float4 p  = *(const float4*)(peq + (size_t)(m & (T_-1)) * D_ + c4);
    float x[4] = { qv.x + 32.f*p.x, qv.y + 32.f*p.y, qv.z + 32.f*p.z, qv.w + 32.f*p.w };
    ushort4 h, l;
    h.x = f2b(x[0]); h.y = f2b(x[1]); h.z = f2b(x[2]); h.w = f2b(x[3]);
    l.x = f2b(x[0] - b2f(h.x)); l.y = f2b(x[1] - b2f(h.y));
    l.z = f2b(x[2] - b2f(h.z)); l.w = f2b(x[3] - b2f(h.w));
    *(ushort4*)(A2 + (size_t)m * 2048 + c4) = h;
    *(ushort4*)(A2 + (size_t)m * 2048 + 1024 + c4) = l;
    *(ushort4*)(q16 + (size_t)m * 1024 + c4) = h;
}

// ---------------- conv: A2k = [hi(k_in)|lo(k_in)] ----------------
__global__ __launch_bounds__(256) void conv_k(const float* __restrict__ q,
                                              const float* __restrict__ peq,
                                              const float* __restrict__ pek,
                                              unsigned short* __restrict__ A2)
{
    int i = blockIdx.x * 256 + threadIdx.x;
    int m = i >> 8, c4 = (i & 255) << 2;
    float4 qv = *(const float4*)(q + (size_t)m * D_ + c4);
    float4 p  = *(const float4*)(peq + (size_t)(m & (T_-1)) * D_ + c4);
    float4 pk = *(const float4*)(pek + (size_t)(m & (T_-1)) * D_ + c4);
    float x[4] = { qv.x + 32.f*(p.x+pk.x), qv.y + 32.f*(p.y+pk.y),
                   qv.z + 32.f*(p.z+pk.z), qv.w + 32.f*(p.w+pk.w) };
    ushort4 h, l;
    h.x = f2b(x[0]); h.y = f2b(x[1]); h.z = f2b(x[2]); h.w = f2b(x[3]);
    l.x = f2b(x[0] - b2f(h.x)); l.y = f2b(x[1] - b2f(h.y));
    l.z = f2b(x[2] - b2f(h.z)); l.w = f2b(x[3] - b2f(h.w));
    *(ushort4*)(A2 + (size_t)m * 2048 + c4) = h;
    *(ushort4*)(A2 + (size_t)m * 2048 + 1024 + c4) = l;
}

// ---------------- conv: weight 1024x1024 -> B2=[n][hi|hi_dup], Blo=[n][lo] ----------------
__global__ __launch_bounds__(256) void conv_wsplit(const float* __restrict__ W,
                                                   unsigned short* __restrict__ B2,
                                                   unsigned short* __restrict__ Blo)
{
    __shared__ float t[32][33];
    int k0 = blockIdx.y * 32, n0 = blockIdx.x * 32;
    int r = threadIdx.x >> 5, c = threadIdx.x & 31;
    #pragma unroll
    for (int rr = 0; rr < 4; ++rr)
        t[r + 8*rr][c] = W[(size_t)(k0 + r + 8*rr) * 1024 + n0 + c];
    __syncthreads();
    #pragma unroll
    for (int rr = 0; rr < 4; ++rr) {
        float v = t[c][r + 8*rr];
        unsigned short h = f2b(v);
        unsigned short l = f2b(v - b2f(h));
        size_t o = (size_t)(n0 + r + 8*rr) * 2048 + k0 + c;
        B2[o] = h; B2[o + 1024] = h;
        Blo[(size_t)(n0 + r + 8*rr) * 1024 + k0 + c] = l;
    }
}

// ---------------- conv: plain transpose+bf16: WT[n][k] = bf16(W[k][n]) ----------------
__global__ __launch_bounds__(256) void conv_wT(const float* __restrict__ W,
                                               unsigned short* __restrict__ WT,
                                               int K, int N)
{
    __shared__ float t[32][33];
    int k0 = blockIdx.y * 32, n0 = blockIdx.x * 32;
    int r = threadIdx.x >> 5, c = threadIdx.x & 31;
    #pragma unroll
    for (int rr = 0; rr < 4; ++rr)
        t[r + 8*rr][c] = W[(size_t)(k0 + r + 8*rr) * N + n0 + c];
    __syncthreads();
    #pragma unroll
    for (int rr = 0; rr < 4; ++rr)
        WT[(size_t)(n0 + r + 8*rr) * K + k0 + c] = f2b(t[c][r + 8*rr]);
}

// ---------------- bf16 MFMA GEMM: C = A[M][lda] @ B_T[N][ldb]^T ----------------
// 128x128 tile, BK=64, 4 waves, each wave 64x64 (4x4 frags of 16x16x32).
// LDS layout chunk-major: chunk c=(k8*128+row), 16B each; global_load_lds linear dest.
// flags: 1 relu | 2 add-f32 | 4 add-bf16 | 8 store-f32 | 16 store-bf16
__global__ __launch_bounds__(256) void gemm_mfma(
    const unsigned short* __restrict__ A, int lda,
    const unsigned short* __restrict__ B, int ldb, int K,
    const float* __restrict__ addf, const unsigned short* __restrict__ addh,
    float* __restrict__ outf, unsigned short* __restrict__ outh,
    int N, int flags)
{
    __shared__ __align__(16) unsigned short As[8192];   // 1024 chunks * 8 bf16
    __shared__ __align__(16) unsigned short Bs[8192];
    const int tid = threadIdx.x;
    const int m0 = blockIdx.y << 7, n0 = blockIdx.x << 7;
    const int lane = tid & 63, wave = tid >> 6;
    const int wm = (wave >> 1) << 6, wn = (wave & 1) << 6;
    const int rl = lane & 15, kg = lane >> 4;

    const unsigned short* gA[4]; const unsigned short* gB[4];
    unsigned short* lA[4]; unsigned short* lB[4];
    #pragma unroll
    for (int i = 0; i < 4; ++i) {
        int c = i * 256 + tid;
        gA[i] = A + (size_t)(m0 + (c & 127)) * lda + (c >> 7) * 8;
        gB[i] = B + (size_t)(n0 + (c & 127)) * ldb + (c >> 7) * 8;
        lA[i] = &As[c * 8];
        lB[i] = &Bs[c * 8];
    }

    f32x4 acc[4][4];
    #pragma unroll
    for (int i = 0; i < 4; ++i)
        #pragma unroll
        for (int j = 0; j < 4; ++j) {
            acc[i][j][0] = 0.f; acc[i][j][1] = 0.f;
            acc[i][j][2] = 0.f; acc[i][j][3] = 0.f;
        }

    for (int k0 = 0; k0 < K; k0 += 64) {
        #pragma unroll
        for (int i = 0; i < 4; ++i) {
            gl_lds16(gA[i] + k0, lA[i]);
            gl_lds16(gB[i] + k0, lB[i]);
        }
        __syncthreads();
        bf16x8 av[2][4], bv[2][4];
        #pragma unroll
        for (int t = 0; t < 2; ++t)
            #pragma unroll
            for (int f = 0; f < 4; ++f) {
                av[t][f] = *(const bf16x8*)&As[(((t*4 + kg) << 7) + wm + (f << 4) + rl) * 8];
                bv[t][f] = *(const bf16x8*)&Bs[(((t*4 + kg) << 7) + wn + (f << 4) + rl) * 8];
            }
        #pragma unroll
        for (int fm = 0; fm < 4; ++fm)
            #pragma unroll
            for (int fn = 0; fn < 4; ++fn) {
                acc[fm][fn] = __builtin_amdgcn_mfma_f32_16x16x32_bf16(av[0][fm], bv[0][fn], acc[fm][fn], 0, 0, 0);
                acc[fm][fn] = __builtin_amdgcn_mfma_f32_16x16x32_bf16(av[1][fm], bv[1][fn], acc[fm][fn], 0, 0, 0);
            }
        __syncthreads();
    }

    // epilogue: C/D layout col=lane&15, row=(lane>>4)*4+reg  [verified m89/m91]
    #pragma unroll
    for (int fm = 0; fm < 4; ++fm) {
        int row = m0 + wm + (fm << 4) + (kg << 2);
        #pragma unroll
        for (int fn = 0; fn < 4; ++fn) {
            int col = n0 + wn + (fn << 4) + rl;
            #pragma unroll
            for (int r = 0; r < 4; ++r) {
                float x = acc[fm][fn][r];
                size_t idx = (size_t)(row + r) * N + col;
                if (flags & 2)  x += addf[idx];
                if (flags & 4)  x += b2f(addh[idx]);
                if (flags & 1)  x = fmaxf(x, 0.f);
                if (flags & 8)  outf[idx] = x;
                if (flags & 16) outh[idx] = f2b(x);
            }
        }
    }
}

// ---------------- flash-style fp32 attention; residual in bf16 in-place ----------------
__global__ __launch_bounds__(256) void attn(const float* __restrict__ Q,
                                            const float* __restrict__ Kp,
                                            const float* __restrict__ Vp,
                                            unsigned short* __restrict__ q16,  // in: bf16(q_in); out: res16
                                            const int* __restrict__ qlens,
                                            const int* __restrict__ klens)
{
    __shared__ __align__(16) float QsT[64][68];
    __shared__ __align__(16) float KP[64][68];
    __shared__ __align__(16) float Vs[64][68];
    __shared__ float rowm[64], rowl[64], rowfac[64];

    const int tid = threadIdx.x;
    const int qt = blockIdx.x, h = blockIdx.y, b = blockIdx.z;
    const int qbase = qt * 64;
    const int qlen = qlens[b], klen = klens[b];
    if (qbase >= qlen) return;   // masked q-tile: res16 already holds bf16(q_in)

    {
        int r = tid >> 2;
        int cc = (tid & 3) * 16;
        const float* src = Q + ((size_t)(b * T_ + qbase + r)) * D_ + h * DH_ + cc;
        #pragma unroll
        for (int u = 0; u < 4; ++u) {
            float4 v = *(const float4*)(src + u * 4);
            QsT[cc + u*4 + 0][r] = v.x; QsT[cc + u*4 + 1][r] = v.y;
            QsT[cc + u*4 + 2][r] = v.z; QsT[cc + u*4 + 3][r] = v.w;
        }
    }
    if (tid < 64) { rowm[tid] = -3.0e38f; rowl[tid] = 0.f; }

    const int q0 = (tid >> 4) * 4;
    const int c0 = (tid & 15) * 4;
    float acc[4][4] = {};

    const int nt = (klen == 1) ? (T_/64) : ((klen + 63) >> 6);   // klen==1: all-NEG row needs full softmax
    for (int kb = 0; kb < nt; ++kb) {
        const int kbase = kb * 64;
        __syncthreads();
        {
            int r = tid >> 2;
            int cc = (tid & 3) * 16;
            const float* ksrc = Kp + ((size_t)(b * T_ + kbase + r)) * D_ + h * DH_ + cc;
            const float* vsrc = Vp + ((size_t)(b * T_ + kbase + r)) * D_ + h * DH_ + cc;
            #pragma unroll
            for (int u = 0; u < 4; ++u) {
                float4 v = *(const float4*)(ksrc + u * 4);
                KP[cc + u*4 + 0][r] = v.x; KP[cc + u*4 + 1][r] = v.y;
                KP[cc + u*4 + 2][r] = v.z; KP[cc + u*4 + 3][r] = v.w;
                *(float4*)&Vs[r][cc + u*4] = *(const float4*)(vsrc + u * 4);
            }
        }
        __syncthreads();
        float s[4][4] = {};
        #pragma unroll 8
        for (int d = 0; d < 64; ++d) {
            float4 qa = *(float4*)&QsT[d][q0];
            float4 ka = *(float4*)&KP[d][c0];
            float qv[4] = {qa.x, qa.y, qa.z, qa.w};
            float kv[4] = {ka.x, ka.y, ka.z, ka.w};
            #pragma unroll
            for (int i = 0; i < 4; ++i)
                #pragma unroll
                for (int j = 0; j < 4; ++j) s[i][j] += qv[i] * kv[j];
        }
        __syncthreads();
        #pragma unroll
        for (int i = 0; i < 4; ++i) {
            int gq = qbase + q0 + i;
            #pragma unroll
            for (int j = 0; j < 4; ++j) {
                int gk = kbase + c0 + j;
                float v = s[i][j] * 0.125f;
                if (gk >= klen || gk == gq) v = NEG_;
                KP[c0 + j][q0 + i] = v;
            }
        }
        __syncthreads();
        {
            int q = tid >> 2, g = tid & 3;
            float mx = -3.0e38f;
            #pragma unroll
            for (int kk = 0; kk < 16; ++kk) mx = fmaxf(mx, KP[g * 16 + kk][q]);
            mx = fmaxf(mx, __shfl_xor(mx, 1));
            mx = fmaxf(mx, __shfl_xor(mx, 2));
            float mold = rowm[q];
            float mnew = fmaxf(mold, mx);
            float sum = 0.f;
            #pragma unroll
            for (int kk = 0; kk < 16; ++kk) {
                int k = g * 16 + kk;
                float p = __expf(KP[k][q] - mnew);
                KP[k][q] = p;
                sum += p;
            }
            sum += __shfl_xor(sum, 1);
            sum += __shfl_xor(sum, 2);
            float fac = __expf(mold - mnew);
            if (g == 0) { rowm[q] = mnew; rowl[q] = rowl[q] * fac + sum; rowfac[q] = fac; }
        }
        __syncthreads();
        {
            float f[4];
            #pragma unroll
            for (int i = 0; i < 4; ++i) f[i] = rowfac[q0 + i];
            #pragma unroll
            for (int i = 0; i < 4; ++i)
                #pragma unroll
                for (int j = 0; j < 4; ++j) acc[i][j] *= f[i];
            #pragma unroll 8
            for (int k = 0; k < 64; ++k) {
                float4 pa = *(float4*)&KP[k][q0];
                float4 vb = *(float4*)&Vs[k][c0];
                float pv[4] = {pa.x, pa.y, pa.z, pa.w};
                float vv[4] = {vb.x, vb.y, vb.z, vb.w};
                #pragma unroll
                for (int i = 0; i < 4; ++i)
                    #pragma unroll
                    for (int j = 0; j < 4; ++j) acc[i][j] += pv[i] * vv[j];
            }
        }
    }
    #pragma unroll
    for (int i = 0; i < 4; ++i) {
        int gq = qbase + q0 + i;
        float qm = (gq < qlen) ? 1.f : 0.f;
        float invl = qm / rowl[q0 + i];
        size_t off = ((size_t)(b * T_ + gq)) * D_ + h * DH_ + c0;
        ushort4 r4 = *(const ushort4*)(q16 + off);
        ushort4 o;
        o.x = f2b(acc[i][0] * invl + b2f(r4.x));
        o.y = f2b(acc[i][1] * invl + b2f(r4.y));
        o.z = f2b(acc[i][2] * invl + b2f(r4.z));
        o.w = f2b(acc[i][3] * invl + b2f(r4.w));
        *(ushort4*)(q16 + off) = o;
    }
}

// ---------------- mean over T ----------------
__global__ __launch_bounds__(256) void mean_kernel(const float* __restrict__ res,
                                                   float* __restrict__ out)
{
    __shared__ float part[4][64];
    int tid = threadIdx.x;
    int b = blockIdx.x >> 4;
    int dbase = (blockIdx.x & 15) * 64;
    int tq = tid >> 6, dd = tid & 63;
    int d = dbase + dd;
    float s = 0.f;
    const float* p = res + ((size_t)b * T_ + tq * 256) * D_ + d;
    for (int t = 0; t < 256; ++t) s += p[(size_t)t * D_];
    part[tq][dd] = s;
    __syncthreads();
    if (tq == 0)
        out[b * D_ + d] = (part[0][dd] + part[1][dd] + part[2][dd] + part[3][dd]) * (1.f / 1024.f);
}

extern "C" void kernel_launch(void* const* d_in, const int* in_sizes, int n_in,
                              void* d_out, int out_size, void* d_ws, size_t ws_size,
                              hipStream_t stream)
{
    const float* queries = (const float*)d_in[0];
    const int*   qlens   = (const int*)d_in[2];
    const int*   klens   = (const int*)d_in[3];
    const float* pe_q    = (const float*)d_in[4];
    const float* pe_k    = (const float*)d_in[5];
    const float* Wq      = (const float*)d_in[6];
    const float* Wk      = (const float*)d_in[7];
    const float* Wv      = (const float*)d_in[8];
    const float* fw1     = (const float*)d_in[9];
    const float* fw2     = (const float*)d_in[10];
    float* out = (float*)d_out;

    // arena (byte offsets, peak 72 MB)
    char* w = (char*)d_ws;
    unsigned short* q16  = (unsigned short*)(w + 0);              // 8 MB; becomes res16 in-place
    float*          Qb   = (float*)(w + (8ll  << 20));            // 16 MB
    float*          Kb   = (float*)(w + (24ll << 20));            // 16 MB
    unsigned short* A2   = (unsigned short*)(w + (40ll << 20));   // 16 MB (A2q -> A2k -> Vb)
    float*          Vb   = (float*)(w + (40ll << 20));
    unsigned short* WB2  = (unsigned short*)(w + (56ll << 20));   // 4 MB
    unsigned short* WBlo = (unsigned short*)(w + (60ll << 20));   // 2 MB
    unsigned short* WvT  = (unsigned short*)(w + (62ll << 20));   // 2 MB
    unsigned short* Kb16 = (unsigned short*)(w + (64ll << 20));   // 8 MB
    unsigned short* h1   = (unsigned short*)(w + (8ll  << 20));   // 32 MB (over Qb+Kb, post-attn)
    unsigned short* fw1T = (unsigned short*)(w + (40ll << 20));   // 8 MB (over Vb, post-attn)
    unsigned short* fw2T = (unsigned short*)(w + (48ll << 20));   // 8 MB
    float*          resf = (float*)(w + (56ll << 20));            // 16 MB (over weights/Kb16)

    dim3 g1024(8, 32);     // N=1024 GEMMs
    dim3 g4096(32, 32);    // FFN1

    // Q projection: Qb = (Ah+Al)@Wh + Ah@Wl
    conv_q<<<4096, 256, 0, stream>>>(queries, pe_q, A2, q16);
    conv_wsplit<<<dim3(32, 32), 256, 0, stream>>>(Wq, WB2, WBlo);
    gemm_mfma<<<g1024, 256, 0, stream>>>(A2, 2048, WB2, 2048, 2048,
                                         nullptr, nullptr, Qb, nullptr, 1024, 8);
    gemm_mfma<<<g1024, 256, 0, stream>>>(A2, 2048, WBlo, 1024, 1024,
                                         Qb, nullptr, Qb, nullptr, 1024, 2 | 8);
    // K projection (k_in = q_in + 32*pe_k), also emit bf16 K
    conv_k<<<4096, 256, 0, stream>>>(queries, pe_q, pe_k, A2);
    conv_wsplit<<<dim3(32, 32), 256, 0, stream>>>(Wk, WB2, WBlo);
    gemm_mfma<<<g1024, 256, 0, stream>>>(A2, 2048, WB2, 2048, 2048,
                                         nullptr, nullptr, Kb, nullptr, 1024, 8);
    gemm_mfma<<<g1024, 256, 0, stream>>>(A2, 2048, WBlo, 1024, 1024,
                                         Kb, nullptr, Kb, Kb16, 1024, 2 | 8 | 16);
    // V = K @ Wv (plain bf16)
    conv_wT<<<dim3(32, 32), 256, 0, stream>>>(Wv, WvT, 1024, 1024);
    gemm_mfma<<<g1024, 256, 0, stream>>>(Kb16, 1024, WvT, 1024, 1024,
                                         nullptr, nullptr, Vb, nullptr, 1024, 8);
    // attention (fp32 core) + residual -> res16 (in-place over q16)
    attn<<<dim3(16, 16, 4), 256, 0, stream>>>(Qb, Kb, Vb, q16, qlens, klens);
    // FFN
    conv_wT<<<dim3(128, 32), 256, 0, stream>>>(fw1, fw1T, 1024, 4096);
    conv_wT<<<dim3(32, 128), 256, 0, stream>>>(fw2, fw2T, 4096, 1024);
    gemm_mfma<<<g4096, 256, 0, stream>>>(q16, 1024, fw1T, 1024, 1024,
                                         nullptr, nullptr, nullptr, h1, 4096, 1 | 16);
    gemm_mfma<<<g1024, 256, 0, stream>>>(h1, 4096, fw2T, 4096, 4096,
                                         nullptr, q16, resf, nullptr, 1024, 4 | 8);
    // mean over T
    mean_kernel<<<dim3(64), 256, 0, stream>>>(resf, out);
}

// Round 3
// 550.252 us; speedup vs baseline: 2.8579x; 1.1720x over previous
//
#include <hip/hip_runtime.h>

#define T_ 1024
#define D_ 1024
#define B_ 4
#define H_ 16
#define DH_ 64
#define M_ (B_*T_)                 // 4096
#define NEG_ (-4294967295.0f)

typedef __attribute__((ext_vector_type(8))) short bf16x8;
typedef __attribute__((ext_vector_type(4))) float f32x4;

__device__ __forceinline__ float b2f(unsigned short u) {
    union { unsigned int i; float f; } v; v.i = ((unsigned int)u) << 16; return v.f;
}
__device__ __forceinline__ unsigned short f2b(float f) {
    unsigned int x = __float_as_uint(f);
    return (unsigned short)((x + 0x7fffu + ((x >> 16) & 1u)) >> 16);
}

typedef const unsigned int __attribute__((address_space(1)))* gas_p;
typedef unsigned int __attribute__((address_space(3)))* las_p;
__device__ __forceinline__ void gl_lds16(const void* g, void* l) {
    __builtin_amdgcn_global_load_lds((gas_p)g, (las_p)l, 16, 0, 0);
}

// ---------------- conv: A3q = [hi|lo|hi](q_in), q16 = hi(q_in) ----------------
__global__ __launch_bounds__(256) void conv_q(const float* __restrict__ q,
                                              const float* __restrict__ peq,
                                              unsigned short* __restrict__ A3,
                                              unsigned short* __restrict__ q16)
{
    int i = blockIdx.x * 256 + threadIdx.x;
    int m = i >> 8, c4 = (i & 255) << 2;
    float4 qv = *(const float4*)(q + (size_t)m * D_ + c4);
    float4 p  = *(const float4*)(peq + (size_t)(m & (T_-1)) * D_ + c4);
    float x[4] = { qv.x + 32.f*p.x, qv.y + 32.f*p.y, qv.z + 32.f*p.z, qv.w + 32.f*p.w };
    ushort4 h, l;
    h.x = f2b(x[0]); h.y = f2b(x[1]); h.z = f2b(x[2]); h.w = f2b(x[3]);
    l.x = f2b(x[0] - b2f(h.x)); l.y = f2b(x[1] - b2f(h.y));
    l.z = f2b(x[2] - b2f(h.z)); l.w = f2b(x[3] - b2f(h.w));
    size_t base = (size_t)m * 3072;
    *(ushort4*)(A3 + base + c4) = h;
    *(ushort4*)(A3 + base + 1024 + c4) = l;
    *(ushort4*)(A3 + base + 2048 + c4) = h;
    *(ushort4*)(q16 + (size_t)m * 1024 + c4) = h;
}

// ---------------- conv: A3pe = [hi|lo|hi](32*pe_k), M=1024 ----------------
__global__ __launch_bounds__(256) void conv_pe3(const float* __restrict__ pek,
                                                unsigned short* __restrict__ A3)
{
    int i = blockIdx.x * 256 + threadIdx.x;
    int m = i >> 8, c4 = (i & 255) << 2;
    float4 p = *(const float4*)(pek + (size_t)m * D_ + c4);
    float x[4] = { 32.f*p.x, 32.f*p.y, 32.f*p.z, 32.f*p.w };
    ushort4 h, l;
    h.x = f2b(x[0]); h.y = f2b(x[1]); h.z = f2b(x[2]); h.w = f2b(x[3]);
    l.x = f2b(x[0] - b2f(h.x)); l.y = f2b(x[1] - b2f(h.y));
    l.z = f2b(x[2] - b2f(h.z)); l.w = f2b(x[3] - b2f(h.w));
    size_t base = (size_t)m * 3072;
    *(ushort4*)(A3 + base + c4) = h;
    *(ushort4*)(A3 + base + 1024 + c4) = l;
    *(ushort4*)(A3 + base + 2048 + c4) = h;
}

// ---------------- conv: [Wq|Wk] -> B3qk rows n in [0,2048), [hi|hi|lo], ld 3072 ----------------
__global__ __launch_bounds__(256) void conv_w3(const float* __restrict__ Wq,
                                               const float* __restrict__ Wk,
                                               unsigned short* __restrict__ B3)
{
    __shared__ float t[32][33];
    const float* W = blockIdx.z ? Wk : Wq;
    int k0 = blockIdx.y * 32, n0 = blockIdx.x * 32;
    int r = threadIdx.x >> 5, c = threadIdx.x & 31;
    #pragma unroll
    for (int rr = 0; rr < 4; ++rr)
        t[r + 8*rr][c] = W[(size_t)(k0 + r + 8*rr) * 1024 + n0 + c];
    __syncthreads();
    #pragma unroll
    for (int rr = 0; rr < 4; ++rr) {
        float v = t[c][r + 8*rr];
        unsigned short h = f2b(v);
        unsigned short l = f2b(v - b2f(h));
        size_t o = (size_t)(blockIdx.z * 1024 + n0 + r + 8*rr) * 3072 + k0 + c;
        B3[o] = h; B3[o + 1024] = h; B3[o + 2048] = l;
    }
}

// ---------------- conv: WT[n][k] = bf16(W[k][n]) ----------------
__global__ __launch_bounds__(256) void conv_wT(const float* __restrict__ W,
                                               unsigned short* __restrict__ WT,
                                               int K, int N)
{
    __shared__ float t[32][33];
    int k0 = blockIdx.y * 32, n0 = blockIdx.x * 32;
    int r = threadIdx.x >> 5, c = threadIdx.x & 31;
    #pragma unroll
    for (int rr = 0; rr < 4; ++rr)
        t[r + 8*rr][c] = W[(size_t)(k0 + r + 8*rr) * N + n0 + c];
    __syncthreads();
    #pragma unroll
    for (int rr = 0; rr < 4; ++rr)
        WT[(size_t)(n0 + r + 8*rr) * K + k0 + c] = f2b(t[c][r + 8*rr]);
}

// ---------------- bf16 MFMA GEMM: C = A[M][lda] @ B_T[N][ldb]^T ----------------
// BM x 128 tile, BK=64, 4 waves. BM=128: waves 2x2 (64x64 each); BM=64: waves 1x4 (64x32).
// CONVA: A is f32, converted to bf16 during reg-staged LDS write.
// flags: 1 relu | 2 add-f32 | 4 add-bf16 | 8 store-f32 | 16 store-bf16 | 32 QK-epilogue
template<int BM, bool CONVA>
__global__ __launch_bounds__(256) void gemm_mfma(
    const void* __restrict__ Ap, int lda,
    const unsigned short* __restrict__ B, int ldb, int K,
    const float* __restrict__ addf, const unsigned short* __restrict__ addh,
    float* __restrict__ outf, float* __restrict__ outf2,
    unsigned short* __restrict__ outh, int N, int flags)
{
    constexpr int LOGBM = (BM == 128) ? 7 : 6;
    constexpr int WN = (BM == 128) ? 2 : 4;     // waves along n
    constexpr int FN = 8 / WN;                   // n-frags per wave: 4 or 2
    constexpr int NA = BM / 32;                  // A chunks per thread: 4 or 2
    __shared__ __align__(16) unsigned short As[BM * 64];
    __shared__ __align__(16) unsigned short Bs[128 * 64];
    const int tid = threadIdx.x;
    const int m0 = blockIdx.y * BM, n0 = blockIdx.x << 7;
    const int lane = tid & 63, wave = tid >> 6;
    const int wm = (wave / WN) * 64;
    const int wn = (wave % WN) * (128 / WN);
    const int rl = lane & 15, kg = lane >> 4;

    const unsigned short* gA[NA]; const float* gAf[NA]; unsigned short* lA[NA];
    const unsigned short* gB[4]; unsigned short* lB[4];
    #pragma unroll
    for (int i = 0; i < NA; ++i) {
        int c = i * 256 + tid;
        int row = c & (BM - 1), k8 = c >> LOGBM;
        if constexpr (CONVA) gAf[i] = (const float*)Ap + (size_t)(m0 + row) * lda + k8 * 8;
        else                 gA[i]  = (const unsigned short*)Ap + (size_t)(m0 + row) * lda + k8 * 8;
        lA[i] = &As[c * 8];
    }
    #pragma unroll
    for (int i = 0; i < 4; ++i) {
        int c = i * 256 + tid;
        gB[i] = B + (size_t)(n0 + (c & 127)) * ldb + (c >> 7) * 8;
        lB[i] = &Bs[c * 8];
    }

    f32x4 acc[4][FN];
    #pragma unroll
    for (int i = 0; i < 4; ++i)
        #pragma unroll
        for (int j = 0; j < FN; ++j) {
            acc[i][j][0] = 0.f; acc[i][j][1] = 0.f;
            acc[i][j][2] = 0.f; acc[i][j][3] = 0.f;
        }

    for (int k0 = 0; k0 < K; k0 += 64) {
        #pragma unroll
        for (int i = 0; i < 4; ++i) gl_lds16(gB[i] + k0, lB[i]);
        if constexpr (CONVA) {
            #pragma unroll
            for (int i = 0; i < NA; ++i) {
                const float* p = gAf[i] + k0;
                float4 x0 = *(const float4*)p;
                float4 x1 = *(const float4*)(p + 4);
                ushort4 a, b4;
                a.x = f2b(x0.x); a.y = f2b(x0.y); a.z = f2b(x0.z); a.w = f2b(x0.w);
                b4.x = f2b(x1.x); b4.y = f2b(x1.y); b4.z = f2b(x1.z); b4.w = f2b(x1.w);
                *(ushort4*)(lA[i]) = a;
                *(ushort4*)(lA[i] + 4) = b4;
            }
        } else {
            #pragma unroll
            for (int i = 0; i < NA; ++i) gl_lds16(gA[i] + k0, lA[i]);
        }
        __syncthreads();
        bf16x8 av[2][4], bv[2][FN];
        #pragma unroll
        for (int t = 0; t < 2; ++t) {
            #pragma unroll
            for (int f = 0; f < 4; ++f)
                av[t][f] = *(const bf16x8*)&As[(((t*4 + kg) << LOGBM) + wm + (f << 4) + rl) * 8];
            #pragma unroll
            for (int f = 0; f < FN; ++f)
                bv[t][f] = *(const bf16x8*)&Bs[(((t*4 + kg) << 7) + wn + (f << 4) + rl) * 8];
        }
        #pragma unroll
        for (int fm = 0; fm < 4; ++fm)
            #pragma unroll
            for (int fn = 0; fn < FN; ++fn) {
                acc[fm][fn] = __builtin_amdgcn_mfma_f32_16x16x32_bf16(av[0][fm], bv[0][fn], acc[fm][fn], 0, 0, 0);
                acc[fm][fn] = __builtin_amdgcn_mfma_f32_16x16x32_bf16(av[1][fm], bv[1][fn], acc[fm][fn], 0, 0, 0);
            }
        __syncthreads();
    }

    // C/D layout: col=lane&15, row=(lane>>4)*4+reg
    #pragma unroll
    for (int fm = 0; fm < 4; ++fm) {
        int row = m0 + wm + (fm << 4) + (kg << 2);
        #pragma unroll
        for (int fn = 0; fn < FN; ++fn) {
            int col = n0 + wn + (fn << 4) + rl;
            #pragma unroll
            for (int r = 0; r < 4; ++r) {
                float x = acc[fm][fn][r];
                int rr = row + r;
                if (flags & 32) {
                    // QK: cols [0,1024) -> outf (Q); [1024,2048) -> +PEKW -> outf2 (K)
                    if (col < 1024) {
                        outf[(size_t)rr * 1024 + col] = x;
                    } else {
                        int c = col - 1024;
                        x += addf[(size_t)(rr & (T_-1)) * 1024 + c];
                        outf2[(size_t)rr * 1024 + c] = x;
                    }
                } else {
                    size_t idx = (size_t)rr * N + col;
                    if (flags & 2)  x += addf[idx];
                    if (flags & 4)  x += b2f(addh[idx]);
                    if (flags & 1)  x = fmaxf(x, 0.f);
                    if (flags & 8)  outf[idx] = x;
                    if (flags & 16) outh[idx] = f2b(x);
                }
            }
        }
    }
}

// ---------------- flash-style fp32 attention; residual in bf16 in-place ----------------
__global__ __launch_bounds__(256) void attn(const float* __restrict__ Q,
                                            const float* __restrict__ Kp,
                                            const float* __restrict__ Vp,
                                            unsigned short* __restrict__ q16,
                                            const int* __restrict__ qlens,
                                            const int* __restrict__ klens)
{
    __shared__ __align__(16) float QsT[64][68];
    __shared__ __align__(16) float KP[64][68];
    __shared__ __align__(16) float Vs[64][68];
    __shared__ float rowm[64], rowl[64], rowfac[64];

    const int tid = threadIdx.x;
    const int qt = blockIdx.x, h = blockIdx.y, b = blockIdx.z;
    const int qbase = qt * 64;
    const int qlen = qlens[b], klen = klens[b];
    if (qbase >= qlen) return;

    {
        int r = tid >> 2;
        int cc = (tid & 3) * 16;
        const float* src = Q + ((size_t)(b * T_ + qbase + r)) * D_ + h * DH_ + cc;
        #pragma unroll
        for (int u = 0; u < 4; ++u) {
            float4 v = *(const float4*)(src + u * 4);
            QsT[cc + u*4 + 0][r] = v.x; QsT[cc + u*4 + 1][r] = v.y;
            QsT[cc + u*4 + 2][r] = v.z; QsT[cc + u*4 + 3][r] = v.w;
        }
    }
    if (tid < 64) { rowm[tid] = -3.0e38f; rowl[tid] = 0.f; }

    const int q0 = (tid >> 4) * 4;
    const int c0 = (tid & 15) * 4;
    float acc[4][4] = {};

    const int nt = (klen == 1) ? (T_/64) : ((klen + 63) >> 6);
    for (int kb = 0; kb < nt; ++kb) {
        const int kbase = kb * 64;
        __syncthreads();
        {
            int r = tid >> 2;
            int cc = (tid & 3) * 16;
            const float* ksrc = Kp + ((size_t)(b * T_ + kbase + r)) * D_ + h * DH_ + cc;
            const float* vsrc = Vp + ((size_t)(b * T_ + kbase + r)) * D_ + h * DH_ + cc;
            #pragma unroll
            for (int u = 0; u < 4; ++u) {
                float4 v = *(const float4*)(ksrc + u * 4);
                KP[cc + u*4 + 0][r] = v.x; KP[cc + u*4 + 1][r] = v.y;
                KP[cc + u*4 + 2][r] = v.z; KP[cc + u*4 + 3][r] = v.w;
                *(float4*)&Vs[r][cc + u*4] = *(const float4*)(vsrc + u * 4);
            }
        }
        __syncthreads();
        float s[4][4] = {};
        #pragma unroll 8
        for (int d = 0; d < 64; ++d) {
            float4 qa = *(float4*)&QsT[d][q0];
            float4 ka = *(float4*)&KP[d][c0];
            float qv[4] = {qa.x, qa.y, qa.z, qa.w};
            float kv[4] = {ka.x, ka.y, ka.z, ka.w};
            #pragma unroll
            for (int i = 0; i < 4; ++i)
                #pragma unroll
                for (int j = 0; j < 4; ++j) s[i][j] += qv[i] * kv[j];
        }
        __syncthreads();
        #pragma unroll
        for (int i = 0; i < 4; ++i) {
            int gq = qbase + q0 + i;
            #pragma unroll
            for (int j = 0; j < 4; ++j) {
                int gk = kbase + c0 + j;
                float v = s[i][j] * 0.125f;
                if (gk >= klen || gk == gq) v = NEG_;
                KP[c0 + j][q0 + i] = v;
            }
        }
        __syncthreads();
        {
            int q = tid >> 2, g = tid & 3;
            float mx = -3.0e38f;
            #pragma unroll
            for (int kk = 0; kk < 16; ++kk) mx = fmaxf(mx, KP[g * 16 + kk][q]);
            mx = fmaxf(mx, __shfl_xor(mx, 1));
            mx = fmaxf(mx, __shfl_xor(mx, 2));
            float mold = rowm[q];
            float mnew = fmaxf(mold, mx);
            float sum = 0.f;
            #pragma unroll
            for (int kk = 0; kk < 16; ++kk) {
                int k = g * 16 + kk;
                float p = __expf(KP[k][q] - mnew);
                KP[k][q] = p;
                sum += p;
            }
            sum += __shfl_xor(sum, 1);
            sum += __shfl_xor(sum, 2);
            float fac = __expf(mold - mnew);
            if (g == 0) { rowm[q] = mnew; rowl[q] = rowl[q] * fac + sum; rowfac[q] = fac; }
        }
        __syncthreads();
        {
            float f[4];
            #pragma unroll
            for (int i = 0; i < 4; ++i) f[i] = rowfac[q0 + i];
            #pragma unroll
            for (int i = 0; i < 4; ++i)
                #pragma unroll
                for (int j = 0; j < 4; ++j) acc[i][j] *= f[i];
            #pragma unroll 8
            for (int k = 0; k < 64; ++k) {
                float4 pa = *(float4*)&KP[k][q0];
                float4 vb = *(float4*)&Vs[k][c0];
                float pv[4] = {pa.x, pa.y, pa.z, pa.w};
                float vv[4] = {vb.x, vb.y, vb.z, vb.w};
                #pragma unroll
                for (int i = 0; i < 4; ++i)
                    #pragma unroll
                    for (int j = 0; j < 4; ++j) acc[i][j] += pv[i] * vv[j];
            }
        }
    }
    #pragma unroll
    for (int i = 0; i < 4; ++i) {
        int gq = qbase + q0 + i;
        float qm = (gq < qlen) ? 1.f : 0.f;
        float invl = qm / rowl[q0 + i];
        size_t off = ((size_t)(b * T_ + gq)) * D_ + h * DH_ + c0;
        ushort4 r4 = *(const ushort4*)(q16 + off);
        ushort4 o;
        o.x = f2b(acc[i][0] * invl + b2f(r4.x));
        o.y = f2b(acc[i][1] * invl + b2f(r4.y));
        o.z = f2b(acc[i][2] * invl + b2f(r4.z));
        o.w = f2b(acc[i][3] * invl + b2f(r4.w));
        *(ushort4*)(q16 + off) = o;
    }
}

// ---------------- mean over T of bf16 [4][1024][X] -> f32 [4][X] ----------------
__global__ __launch_bounds__(256) void mean16(const unsigned short* __restrict__ X,
                                              float* __restrict__ out, int Xdim)
{
    __shared__ float red[4][128];
    int tid = threadIdx.x;
    int b = blockIdx.y;
    int dbase = blockIdx.x * 128;
    int tq = tid >> 6, dd = tid & 63;
    int d = dbase + dd * 2;
    const unsigned short* p = X + ((size_t)b * T_ + tq * 256) * Xdim + d;
    float s0 = 0.f, s1 = 0.f;
    for (int t = 0; t < 256; ++t) {
        ushort2 v = *(const ushort2*)(p + (size_t)t * Xdim);
        s0 += b2f(v.x); s1 += b2f(v.y);
    }
    red[tq][dd*2] = s0; red[tq][dd*2 + 1] = s1;
    __syncthreads();
    if (tq == 0) {
        float a = red[0][dd*2] + red[1][dd*2] + red[2][dd*2] + red[3][dd*2];
        float c = red[0][dd*2+1] + red[1][dd*2+1] + red[2][dd*2+1] + red[3][dd*2+1];
        out[(size_t)b * Xdim + d]     = a * (1.f/1024.f);
        out[(size_t)b * Xdim + d + 1] = c * (1.f/1024.f);
    }
}

// ---------------- out[b][d] = Mres[b][d] + sum_j Hm[b][j]*fw2[j][d] ----------------
__global__ __launch_bounds__(256) void final_out(const float* __restrict__ Mres,
                                                 const float* __restrict__ Hm,
                                                 const float* __restrict__ fw2,
                                                 float* __restrict__ out)
{
    __shared__ float red[4][4][64];
    int tid = threadIdx.x;
    int dd = tid & 63;
    int d = blockIdx.x * 64 + dd;
    int jq = tid >> 6;
    float s[4] = {0.f, 0.f, 0.f, 0.f};
    const float* w = fw2 + (size_t)jq * 1024 * 1024 + d;
    const float* hm = Hm + jq * 1024;
    for (int j = 0; j < 1024; ++j) {
        float wv = w[(size_t)j * 1024];
        s[0] += hm[j] * wv;
        s[1] += hm[4096 + j] * wv;
        s[2] += hm[8192 + j] * wv;
        s[3] += hm[12288 + j] * wv;
    }
    #pragma unroll
    for (int bb = 0; bb < 4; ++bb) red[jq][bb][dd] = s[bb];
    __syncthreads();
    int b = jq;   // reuse 4 row-groups as 4 batches
    float tot = red[0][b][dd] + red[1][b][dd] + red[2][b][dd] + red[3][b][dd];
    out[(size_t)b * 1024 + d] = Mres[(size_t)b * 1024 + d] + tot;
}

extern "C" void kernel_launch(void* const* d_in, const int* in_sizes, int n_in,
                              void* d_out, int out_size, void* d_ws, size_t ws_size,
                              hipStream_t stream)
{
    const float* queries = (const float*)d_in[0];
    const int*   qlens   = (const int*)d_in[2];
    const int*   klens   = (const int*)d_in[3];
    const float* pe_q    = (const float*)d_in[4];
    const float* pe_k    = (const float*)d_in[5];
    const float* Wq      = (const float*)d_in[6];
    const float* Wk      = (const float*)d_in[7];
    const float* Wv      = (const float*)d_in[8];
    const float* fw1     = (const float*)d_in[9];
    const float* fw2     = (const float*)d_in[10];
    float* out = (float*)d_out;

    // arena (MB offsets), peak exactly 80 MB
    char* w = (char*)d_ws;
    unsigned short* q16  = (unsigned short*)(w);                  // [0,8)   res16 in place
    unsigned short* A3q  = (unsigned short*)(w + (8ll  << 20));   // [8,32)
    unsigned short* B3qk = (unsigned short*)(w + (32ll << 20));   // [32,44)
    float*          PEKW = (float*)(w + (44ll << 20));            // [44,48)
    unsigned short* A3pe = (unsigned short*)(w + (48ll << 20));   // [48,54) dead -> Qb
    float*          Qb   = (float*)(w + (48ll << 20));            // [48,64)
    float*          Kb   = (float*)(w + (64ll << 20));            // [64,80)
    float*          Vb   = (float*)(w + (8ll  << 20));            // [8,24)  over dead A3q
    unsigned short* fw1T = (unsigned short*)(w + (24ll << 20));   // [24,32) over dead A3q
    unsigned short* WvT  = (unsigned short*)(w + (32ll << 20));   // [32,34) over dead B3qk
    float*          Mres = (float*)(w + (34ll << 20));            // 16 KB
    float*          Hm   = (float*)(w + (35ll << 20));            // 64 KB
    unsigned short* h1   = (unsigned short*)(w + (44ll << 20));   // [44,76) over dead PEKW/Qb/Kb

    // 1) conversions
    conv_q  <<<4096, 256, 0, stream>>>(queries, pe_q, A3q, q16);
    conv_w3 <<<dim3(32, 32, 2), 256, 0, stream>>>(Wq, Wk, B3qk);
    conv_pe3<<<1024, 256, 0, stream>>>(pe_k, A3pe);
    // 2) PEKW = (32*pe_k) @ Wk   [M=1024,N=1024,K=3072 split]
    gemm_mfma<64,false><<<dim3(8, 16), 256, 0, stream>>>(
        A3pe, 3072, B3qk + (size_t)1024 * 3072, 3072, 3072,
        nullptr, nullptr, PEKW, nullptr, nullptr, 1024, 8);
    // 3) [Q|K] = q_in @ [Wq|Wk] (+PEKW on K half)  [M=4096,N=2048,K=3072]
    gemm_mfma<128,false><<<dim3(16, 32), 256, 0, stream>>>(
        A3q, 3072, B3qk, 3072, 3072,
        PEKW, nullptr, Qb, Kb, nullptr, 2048, 32);
    // 4) V = K @ Wv  (f32 A converted in staging)
    conv_wT<<<dim3(32, 32), 256, 0, stream>>>(Wv, WvT, 1024, 1024);
    gemm_mfma<64,true><<<dim3(8, 64), 256, 0, stream>>>(
        Kb, 1024, WvT, 1024, 1024,
        nullptr, nullptr, Vb, nullptr, nullptr, 1024, 8);
    // 5) attention + residual -> res16 (in-place over q16)
    attn<<<dim3(16, 16, 4), 256, 0, stream>>>(Qb, Kb, Vb, q16, qlens, klens);
    // 6) FFN1: h1 = relu(res @ fw1)  [M=4096,N=4096,K=1024]
    conv_wT<<<dim3(128, 32), 256, 0, stream>>>(fw1, fw1T, 1024, 4096);
    gemm_mfma<128,false><<<dim3(32, 32), 256, 0, stream>>>(
        q16, 1024, fw1T, 1024, 1024,
        nullptr, nullptr, nullptr, nullptr, h1, 4096, 1 | 16);
    // 7) means + final: out = mean_t(res) + mean_t(h1) @ fw2
    mean16<<<dim3(8, 4),  256, 0, stream>>>(q16, Mres, 1024);
    mean16<<<dim3(32, 4), 256, 0, stream>>>(h1, Hm, 4096);
    final_out<<<16, 256, 0, stream>>>(Mres, Hm, fw2, out);
}